// Round 2
// baseline (837.051 us; speedup 1.0000x reference)
//
#include <hip/hip_runtime.h>
#include <cstddef>

#define DIM 256
#define NSLOT 8
#define BATCH 64
#define NTOK 4096
#define SEGB 16                 /* attn blocks per batch */
#define NPART SEGB              /* U/l partials per batch */
#define ITERS 3
#define EPS 1e-5f

typedef short bf16x8 __attribute__((ext_vector_type(8)));
typedef short bf16x4 __attribute__((ext_vector_type(4)));
typedef float f32x4  __attribute__((ext_vector_type(4)));

static __device__ __forceinline__ short f2bf(float f) {
    union { float f; unsigned u; } v; v.f = f;
    unsigned r = v.u + 0x7fffu + ((v.u >> 16) & 1u);   // RNE
    return (short)(r >> 16);
}

// ---------------- workspace layout (float offsets) ----------------
enum : size_t {
    OFF_M     = 0,                               // [256][256]  (Wq^T Wk) * d^-0.5
    OFF_WIHT  = OFF_M    + 256 * 256,            // [256][768]
    OFF_WHHT  = OFF_WIHT + 256 * 768,            // [256][768]
    OFF_WVT   = OFF_WHHT + 256 * 768,            // [256][256]
    OFF_W1T   = OFF_WVT  + 256 * 256,            // [256][256]
    OFF_W2T   = OFF_W1T  + 256 * 256,            // [256][256]
    OFF_SLOTS = OFF_W2T  + 256 * 256,            // [64][8][256]
    OFF_SNEW  = OFF_SLOTS + BATCH * NSLOT * 256, // (unused, layout kept)
    OFF_QT    = OFF_SNEW  + BATCH * NSLOT * 256, // [64][8][256]
    OFF_H     = OFF_QT    + BATCH * NSLOT * 256, // (unused)
    OFF_UPD   = OFF_H     + BATCH * NSLOT * 256, // (unused)
    OFF_UPART = OFF_UPD   + BATCH * NSLOT * 256, // [64][NPART][8][256]
    OFF_LPART = OFF_UPART + (size_t)BATCH * NPART * NSLOT * 256, // [64][NPART][16] (l:0-7)
    OFF_XLN   = OFF_LPART + BATCH * NPART * 16,  // bf16 LN(x) token-major [64][4096][256]
    OFF_XLT   = OFF_XLN   + (size_t)BATCH * NTOK * 128, // bf16 LN(x) tile-transposed [64][64][256][64]
    WS_FLOATS = OFF_XLT   + (size_t)BATCH * NTOK * 128
};

// ---------------- weight transposes (coalesced via LDS tile) ----------------
__global__ __launch_bounds__(256) void k_transpose(const float* __restrict__ w_ih,
                                                   const float* __restrict__ w_hh,
                                                   const float* __restrict__ wv,
                                                   const float* __restrict__ w1,
                                                   const float* __restrict__ w2,
                                                   float* __restrict__ ws) {
    int z = blockIdx.z;
    const float* src;
    float* dst;
    int R;
    if (z == 0)      { src = w_ih; dst = ws + OFF_WIHT; R = 768; }
    else if (z == 1) { src = w_hh; dst = ws + OFF_WHHT; R = 768; }
    else if (z == 2) { src = wv;   dst = ws + OFF_WVT;  R = 256; }
    else if (z == 3) { src = w1;   dst = ws + OFF_W1T;  R = 256; }
    else             { src = w2;   dst = ws + OFF_W2T;  R = 256; }
    if ((int)blockIdx.x * 32 >= R) return;
    __shared__ float tile[32][33];
    int lx = threadIdx.x & 31, ly = threadIdx.x >> 5;
    int r0 = blockIdx.x * 32, c0 = blockIdx.y * 32;
#pragma unroll
    for (int p = 0; p < 4; ++p)
        tile[ly + p * 8][lx] = src[(size_t)(r0 + ly + p * 8) * 256 + c0 + lx];
    __syncthreads();
#pragma unroll
    for (int p = 0; p < 4; ++p)
        dst[(size_t)(c0 + ly + p * 8) * R + r0 + lx] = tile[lx][ly + p * 8];
}

// ---------------- M = (Wq^T @ Wk) * d^-0.5 ----------------
__global__ __launch_bounds__(256) void k_m(const float* __restrict__ wq,
                                           const float* __restrict__ wk,
                                           float* __restrict__ ws) {
    int d = blockIdx.x, t = threadIdx.x;
    float acc = 0.f;
    for (int e = 0; e < 256; ++e)
        acc += wq[e * 256 + d] * wk[e * 256 + t];
    ws[OFF_M + d * 256 + t] = acc * 0.0625f; // 256^-0.5
}

// ---------------- slots init ----------------
__global__ __launch_bounds__(256) void k_init(const float* __restrict__ mu,
                                              const float* __restrict__ logsig,
                                              const float* __restrict__ noise,
                                              float* __restrict__ ws) {
    int i = blockIdx.x * 256 + threadIdx.x; // grid 512 -> 131072
    int d = i & 255;
    ws[OFF_SLOTS + i] = mu[d] + noise[i] * __expf(logsig[d]);
}

// ---------------- k_prep: xln = bf16(LN(x)) in token-major AND tile-transposed ----------------
// grid (SEGB, 64), 256 thr. Reuses the proven scatter-swizzle + gather patterns (once, not 3x).
__global__ __launch_bounds__(256) void k_prep(const float* __restrict__ x,
                                              const float* __restrict__ g_in,
                                              const float* __restrict__ be_in,
                                              float* __restrict__ ws) {
    int seg = blockIdx.x, b = blockIdx.y;
    int t = threadIdx.x;
    int w = t >> 6, lane = t & 63;
    int q = lane >> 4, s16 = lane & 15;

    __shared__ short xT[256 * 64];
    __shared__ float gl[256], bl[256];
    gl[t] = g_in[t];
    bl[t] = be_in[t];
    __syncthreads();

    short* xln = (short*)(ws + OFF_XLN);
    short* xlt = (short*)(ws + OFF_XLT);
    int g0 = ((w * 16 + s16) >> 3);
    int t7 = s16 & 7;

    for (int tt = 0; tt < 4; ++tt) {
        int tok = seg * 256 + tt * 64 + w * 16 + s16;
        const float4* xp = (const float4*)(x + ((size_t)b * NTOK + tok) * 256 + q * 8);
        float4 xa[8], xb[8];
#pragma unroll
        for (int i = 0; i < 8; ++i) { xa[i] = xp[8 * i]; xb[i] = xp[8 * i + 1]; }
        float s1 = 0.f, s2 = 0.f;
#pragma unroll
        for (int i = 0; i < 8; ++i) {
            s1 += xa[i].x + xa[i].y + xa[i].z + xa[i].w + xb[i].x + xb[i].y + xb[i].z + xb[i].w;
            s2 += xa[i].x * xa[i].x + xa[i].y * xa[i].y + xa[i].z * xa[i].z + xa[i].w * xa[i].w
                + xb[i].x * xb[i].x + xb[i].y * xb[i].y + xb[i].z * xb[i].z + xb[i].w * xb[i].w;
        }
        s1 += __shfl_xor(s1, 16); s2 += __shfl_xor(s2, 16);
        s1 += __shfl_xor(s1, 32); s2 += __shfl_xor(s2, 32);
        float mu = s1 * (1.f / 256.f);
        float rstd = rsqrtf(s2 * (1.f / 256.f) - mu * mu + EPS);

        bf16x8 af[8];
#pragma unroll
        for (int i = 0; i < 8; ++i) {
            int dbase = i * 32 + q * 8;
            float4 gA = *(const float4*)&gl[dbase];
            float4 gB = *(const float4*)&gl[dbase + 4];
            float4 bA = *(const float4*)&bl[dbase];
            float4 bB = *(const float4*)&bl[dbase + 4];
            bf16x8 f;
            f[0] = f2bf((xa[i].x - mu) * rstd * gA.x + bA.x);
            f[1] = f2bf((xa[i].y - mu) * rstd * gA.y + bA.y);
            f[2] = f2bf((xa[i].z - mu) * rstd * gA.z + bA.z);
            f[3] = f2bf((xa[i].w - mu) * rstd * gA.w + bA.w);
            f[4] = f2bf((xb[i].x - mu) * rstd * gB.x + bB.x);
            f[5] = f2bf((xb[i].y - mu) * rstd * gB.y + bB.y);
            f[6] = f2bf((xb[i].z - mu) * rstd * gB.z + bB.z);
            f[7] = f2bf((xb[i].w - mu) * rstd * gB.w + bB.w);
            af[i] = f;
        }

        // token-major writeout (directly usable as A-fragments later)
        short* xrow = xln + ((size_t)b * NTOK + tok) * 256;
#pragma unroll
        for (int i = 0; i < 8; ++i)
            *(bf16x8*)&xrow[i * 32 + q * 8] = af[i];

        __syncthreads();   // WAR: previous tile's gather reads of xT done

        // scatter transpose into LDS (XOR-swizzled groups, proven)
#pragma unroll
        for (int i = 0; i < 8; ++i) {
            int Ki = (4 * i + q) & 7;
            int dbase = i * 32 + q * 8;
            bf16x8 f = af[i];
#pragma unroll
            for (int e = 0; e < 8; ++e) {
                int gp = (g0 ^ e ^ Ki) & 7;
                xT[((dbase + e) << 6) + (gp << 3) + t7] = f[e];
            }
        }
        __syncthreads();   // xT ready

        // gather (proven conflict-free pattern) -> plain [d][tok] global layout
        short* xtb = xlt + (size_t)(b * 64 + seg * 4 + tt) * 256 * 64;
#pragma unroll
        for (int c = 0; c < 4; ++c) {
            int d = (4 * w + c) * 16 + s16;
            int swz = (d ^ (d >> 3)) & 7;
            const short* row = &xT[d << 6];
            bf16x8 b0 = *(const bf16x8*)&row[((q ^ swz) & 7) << 3];
            bf16x8 b1 = *(const bf16x8*)&row[(((4 + q) ^ swz) & 7) << 3];
            *(bf16x8*)&xtb[d * 64 + q * 8] = b0;
            *(bf16x8*)&xtb[d * 64 + (q + 4) * 8] = b1;
        }
    }
}

// ---------------- qt = LN(slots, g_sl) @ M  (prologue only) ----------------
__global__ __launch_bounds__(256) void k_qt(float* __restrict__ ws,
                                            const float* __restrict__ g_sl,
                                            const float* __restrict__ be_sl) {
    __shared__ float ln[2048];
    int chunk = blockIdx.x, b = blockIdx.y;
    int t = threadIdx.x, wave = t >> 6, lane = t & 63;
    const float* slots = ws + OFF_SLOTS + b * 2048;
    float4 gf = ((const float4*)g_sl)[lane];
    float4 bf = ((const float4*)be_sl)[lane];
#pragma unroll
    for (int rr = 0; rr < 2; ++rr) {
        int r = wave + rr * 4;
        float4 v = ((const float4*)(slots + r * 256))[lane];
        float s1 = v.x + v.y + v.z + v.w;
        float s2 = v.x * v.x + v.y * v.y + v.z * v.z + v.w * v.w;
#pragma unroll
        for (int m = 1; m < 64; m <<= 1) { s1 += __shfl_xor(s1, m); s2 += __shfl_xor(s2, m); }
        float mu = s1 * (1.f / 256.f);
        float rstd = rsqrtf(s2 * (1.f / 256.f) - mu * mu + EPS);
        float4 o;
        o.x = (v.x - mu) * rstd * gf.x + bf.x;
        o.y = (v.y - mu) * rstd * gf.y + bf.y;
        o.z = (v.z - mu) * rstd * gf.z + bf.z;
        o.w = (v.w - mu) * rstd * gf.w + bf.w;
        *((float4*)&ln[r * 256 + lane * 4]) = o;
    }
    __syncthreads();
    const float* M = ws + OFF_M;
    int k0 = t >> 6;               // wave-uniform
    int e = chunk * 64 + (t & 63);
    float a0 = 0.f, a1 = 0.f;
    for (int d = 0; d < 256; ++d) {
        float m = M[d * 256 + e];
        a0 += ln[k0 * 256 + d] * m;
        a1 += ln[(k0 + 4) * 256 + d] * m;
    }
    float* qt = ws + OFF_QT + b * 2048;
    qt[k0 * 256 + e] = a0;
    qt[(k0 + 4) * 256 + e] = a1;
}

// ---------------- lean MFMA flash attention over precomputed bf16 LN(x) ----------------
// A-frags stream from xln (loads ARE the fragments); U-GEMM B-frags stream from xlnT.
// No LN, no f2bf of x, no LDS transpose. One barrier per tile (Etmp double-buffered).
__global__ __launch_bounds__(256) void k_attn(float* __restrict__ ws) {
    int seg = blockIdx.x, b = blockIdx.y;
    int t = threadIdx.x;
    int w = t >> 6, lane = t & 63;
    int q = lane >> 4, s16 = lane & 15;

    __shared__ short qhi[16 * 264];      // bf16 qt, rows 8-15 zero
    __shared__ short Etmp[2][16 * 72];   // E bf16, [slot][token], double-buffered
    __shared__ float lsum[4][8];

    const float* qtg = ws + OFF_QT + b * 2048;
    for (int idx = t; idx < 16 * 264; idx += 256) {
        int s = idx / 264, d = idx - s * 264;
        qhi[idx] = (s < 8 && d < 256) ? f2bf(qtg[s * 256 + d]) : (short)0;
    }
    __syncthreads();

    bf16x8 qf[8];
#pragma unroll
    for (int i = 0; i < 8; ++i)
        qf[i] = *(const bf16x8*)&qhi[s16 * 264 + i * 32 + q * 8];

    f32x4 U[4];
#pragma unroll
    for (int c = 0; c < 4; ++c) U[c] = (f32x4){0.f, 0.f, 0.f, 0.f};
    float lacc = 0.f;

    const short* xln = (const short*)(ws + OFF_XLN);
    const short* xlt = (const short*)(ws + OFF_XLT);
    int mytok = seg * 256 + w * 16 + s16;

    for (int tt = 0; tt < 4; ++tt) {
        // A-frags: my token's LN'd row, bf16, direct from global
        const short* xr = xln + ((size_t)b * NTOK + mytok + tt * 64) * 256 + q * 8;
        bf16x8 af[8];
#pragma unroll
        for (int i = 0; i < 8; ++i) af[i] = *(const bf16x8*)&xr[i * 32];

        f32x4 Lc = (f32x4){0.f, 0.f, 0.f, 0.f};
#pragma unroll
        for (int i = 0; i < 8; ++i)
            Lc = __builtin_amdgcn_mfma_f32_16x16x32_bf16(af[i], qf[i], Lc, 0, 0, 0);

        bf16x4 e2;
#pragma unroll
        for (int r = 0; r < 4; ++r) {
            float E = __expf(fminf(Lc[r], 30.f));
            lacc += E;
            e2[r] = f2bf(E);
        }
        *(bf16x4*)&Etmp[tt & 1][s16 * 72 + w * 16 + q * 4] = e2;
        __syncthreads();   // Etmp[tt&1] ready (prev buffer reads already safe)

        bf16x8 ea0 = *(const bf16x8*)&Etmp[tt & 1][s16 * 72 + q * 8];
        bf16x8 ea1 = *(const bf16x8*)&Etmp[tt & 1][s16 * 72 + 32 + q * 8];

        // U-GEMM B-frags direct from transposed global layout
        const short* xtb = xlt + (size_t)(b * 64 + seg * 4 + tt) * 256 * 64;
#pragma unroll
        for (int c = 0; c < 4; ++c) {
            int d = (4 * w + c) * 16 + s16;
            bf16x8 b0 = *(const bf16x8*)&xtb[d * 64 + q * 8];
            bf16x8 b1 = *(const bf16x8*)&xtb[d * 64 + (q + 4) * 8];
            U[c] = __builtin_amdgcn_mfma_f32_16x16x32_bf16(ea0, b0, U[c], 0, 0, 0);
            U[c] = __builtin_amdgcn_mfma_f32_16x16x32_bf16(ea1, b1, U[c], 0, 0, 0);
        }
    }

    lacc += __shfl_xor(lacc, 16); lacc += __shfl_xor(lacc, 32);
    __syncthreads();
    if (q == 0 && s16 < 8) lsum[w][s16] = lacc;
    __syncthreads();
    float* lpart = ws + OFF_LPART + (size_t)(b * NPART + seg) * 16;
    if (t < 8) lpart[t] = lsum[0][t] + lsum[1][t] + lsum[2][t] + lsum[3][t];
    float* up = ws + OFF_UPART + (size_t)(b * NPART + seg) * NSLOT * 256;
#pragma unroll
    for (int c = 0; c < 4; ++c) {
        int d = (4 * w + c) * 16 + s16;
#pragma unroll
        for (int r = 0; r < 4; ++r) {
            int slot = q * 4 + r;
            if (slot < 8) up[slot * 256 + d] = U[c][r];
        }
    }
}

// ---------------- wave-per-row LN over 2 rows of [2][256] LDS ----------------
static __device__ __forceinline__ void ln_row2(const float* src, float* dst,
                                               const float* __restrict__ g,
                                               const float* __restrict__ be,
                                               int wave, int lane) {
    if (wave < 2) {
        float4 v = *(const float4*)(src + wave * 256 + lane * 4);
        float s1 = v.x + v.y + v.z + v.w;
        float s2 = v.x * v.x + v.y * v.y + v.z * v.z + v.w * v.w;
#pragma unroll
        for (int m = 1; m < 64; m <<= 1) { s1 += __shfl_xor(s1, m); s2 += __shfl_xor(s2, m); }
        float mu = s1 * (1.f / 256.f);
        float rstd = rsqrtf(s2 * (1.f / 256.f) - mu * mu + EPS);
        float4 gf = ((const float4*)g)[lane];
        float4 bf = ((const float4*)be)[lane];
        float4 o;
        o.x = (v.x - mu) * rstd * gf.x + bf.x;
        o.y = (v.y - mu) * rstd * gf.y + bf.y;
        o.z = (v.z - mu) * rstd * gf.z + bf.z;
        o.w = (v.w - mu) * rstd * gf.w + bf.w;
        *(float4*)(dst + wave * 256 + lane * 4) = o;
    }
}

// ---------------- fused slot pipeline: combine -> updates -> GRU -> MLP -> (qt | out) ----------------
__global__ __launch_bounds__(512) void k_fused(float* __restrict__ ws,
                                               const float* __restrict__ b_ih,
                                               const float* __restrict__ b_hh,
                                               const float* __restrict__ g_ff,
                                               const float* __restrict__ be_ff,
                                               const float* __restrict__ b1p,
                                               const float* __restrict__ b2p,
                                               const float* __restrict__ g_sl,
                                               const float* __restrict__ be_sl,
                                               float* __restrict__ dout) {
    __shared__ __align__(16) float uc[2][256], upd[2][256], sl[2][256], snew[2][256];
    __shared__ __align__(16) float lnb[2][256], hbuf[2][256], so[2][256];
    __shared__ float lsv[2];

    int sp = blockIdx.x, b = blockIdx.y, t = threadIdx.x;
    int s0 = sp * 2;
    int s = t >> 8, d = t & 255;          // s wave-uniform
    int wave = t >> 6, lane = t & 63;

    // ---- Stage A: combine l partials for the 2 slots ----
    if (t < 32) {
        int ss = t >> 4, g = t & 15;
        float lv = ws[OFF_LPART + (size_t)(b * NPART + g) * 16 + s0 + ss];
#pragma unroll
        for (int m = 1; m < 16; m <<= 1) lv += __shfl_xor(lv, m);
        if ((t & 15) == 0) lsv[ss] = lv;
    }

    // ---- Stage B: combine U partials; load old slots ----
    const float* up0 = ws + OFF_UPART + (size_t)b * NPART * NSLOT * 256 + (s0 + s) * 256 + d;
    float acc = 0.f;
#pragma unroll
    for (int g = 0; g < NPART; ++g) acc += up0[(size_t)g * NSLOT * 256];
    sl[s][d] = ws[OFF_SLOTS + (size_t)b * 2048 + (s0 + s) * 256 + d];
    __syncthreads();
    uc[s][d] = acc / lsv[s];
    __syncthreads();

    // ---- Stage C: upd = uc @ WvT ----
    {
        const float* WvT = ws + OFF_WVT;
        float o = 0.f;
        for (int dd = 0; dd < 256; ++dd) o += uc[s][dd] * WvT[dd * 256 + d];
        upd[s][d] = o;
    }
    __syncthreads();

    // ---- Stage D: GRU cell ----
    {
        const float* WihT = ws + OFF_WIHT;
        const float* WhhT = ws + OFF_WHHT;
        float ar = 0.f, az = 0.f, an = 0.f, hr = 0.f, hz = 0.f, hn = 0.f;
        for (int dd = 0; dd < 256; ++dd) {
            float ud = upd[s][dd], sd = sl[s][dd];
            const float* wi = WihT + dd * 768;
            const float* wh = WhhT + dd * 768;
            ar += ud * wi[d];       az += ud * wi[256 + d]; an += ud * wi[512 + d];
            hr += sd * wh[d];       hz += sd * wh[256 + d]; hn += sd * wh[512 + d];
        }
        float rg = 1.f / (1.f + __expf(-(ar + b_ih[d] + hr + b_hh[d])));
        float zg = 1.f / (1.f + __expf(-(az + b_ih[256 + d] + hz + b_hh[256 + d])));
        float ng = tanhf(an + b_ih[512 + d] + rg * (hn + b_hh[512 + d]));
        snew[s][d] = (1.f - zg) * ng + zg * sl[s][d];
    }
    __syncthreads();

    // ---- Stage E: LN(snew, g_ff, be_ff) ----
    ln_row2(&snew[0][0], &lnb[0][0], g_ff, be_ff, wave, lane);
    __syncthreads();

    // ---- Stage F: h = relu(lnb @ W1T + b1) ----
    {
        const float* W1T = ws + OFF_W1T;
        float o = 0.f;
        for (int dd = 0; dd < 256; ++dd) o += lnb[s][dd] * W1T[dd * 256 + d];
        hbuf[s][d] = fmaxf(o + b1p[d], 0.f);
    }
    __syncthreads();

    // ---- Stage G: slots_out = snew + h @ W2T + b2 ----
    {
        const float* W2T = ws + OFF_W2T;
        float o = 0.f;
        for (int dd = 0; dd < 256; ++dd) o += hbuf[s][dd] * W2T[dd * 256 + d];
        float r = snew[s][d] + o + b2p[d];
        so[s][d] = r;
        ws[OFF_SLOTS + (size_t)b * 2048 + (s0 + s) * 256 + d] = r;
        if (dout) dout[(size_t)b * 2048 + (s0 + s) * 256 + d] = r;
    }

    // ---- Stage H (non-final iters): qt = LN(slots_out, g_sl) @ M ----
    if (!dout) {
        __syncthreads();
        ln_row2(&so[0][0], &lnb[0][0], g_sl, be_sl, wave, lane);
        __syncthreads();
        const float* M = ws + OFF_M;
        float o = 0.f;
        for (int dd = 0; dd < 256; ++dd) o += lnb[s][dd] * M[dd * 256 + d];
        ws[OFF_QT + (size_t)b * 2048 + (s0 + s) * 256 + d] = o;
    }
}

extern "C" void kernel_launch(void* const* d_in, const int* in_sizes, int n_in,
                              void* d_out, int out_size, void* d_ws, size_t ws_size,
                              hipStream_t stream) {
    const float* x      = (const float*)d_in[0];
    const float* noise  = (const float*)d_in[1];
    const float* mu     = (const float*)d_in[2];
    const float* logsig = (const float*)d_in[3];
    const float* Wq     = (const float*)d_in[4];
    const float* Wk     = (const float*)d_in[5];
    const float* Wv     = (const float*)d_in[6];
    const float* W_ih   = (const float*)d_in[7];
    const float* W_hh   = (const float*)d_in[8];
    const float* b_ih   = (const float*)d_in[9];
    const float* b_hh   = (const float*)d_in[10];
    const float* W1     = (const float*)d_in[11];
    const float* b1     = (const float*)d_in[12];
    const float* W2     = (const float*)d_in[13];
    const float* b2     = (const float*)d_in[14];
    const float* g_in   = (const float*)d_in[15];
    const float* be_in  = (const float*)d_in[16];
    const float* g_sl   = (const float*)d_in[17];
    const float* be_sl  = (const float*)d_in[18];
    const float* g_ff   = (const float*)d_in[19];
    const float* be_ff  = (const float*)d_in[20];
    float* ws = (float*)d_ws;
    float* out = (float*)d_out;

    hipLaunchKernelGGL(k_transpose, dim3(24, 8, 5), dim3(256), 0, stream, W_ih, W_hh, Wv, W1, W2, ws);
    hipLaunchKernelGGL(k_m, dim3(256), dim3(256), 0, stream, Wq, Wk, ws);
    hipLaunchKernelGGL(k_init, dim3(512), dim3(256), 0, stream, mu, logsig, noise, ws);
    hipLaunchKernelGGL(k_prep, dim3(SEGB, 64), dim3(256), 0, stream, x, g_in, be_in, ws);
    hipLaunchKernelGGL(k_qt, dim3(4, 64), dim3(256), 0, stream, ws, g_sl, be_sl);
    for (int it = 0; it < ITERS; ++it) {
        hipLaunchKernelGGL(k_attn, dim3(SEGB, 64), dim3(256), 0, stream, ws);
        hipLaunchKernelGGL(k_fused, dim3(4, 64), dim3(512), 0, stream, ws,
                           b_ih, b_hh, g_ff, be_ff, b1, b2, g_sl, be_sl,
                           (it == ITERS - 1) ? out : nullptr);
    }
}

// Round 3
// 731.973 us; speedup vs baseline: 1.1436x; 1.1436x over previous
//
#include <hip/hip_runtime.h>
#include <cstddef>

#define DIM 256
#define NSLOT 8
#define BATCH 64
#define NTOK 4096
#define SEGB 16                 /* attn blocks per batch */
#define NPART SEGB              /* U/l partials per batch */
#define ITERS 3
#define EPS 1e-5f

typedef short bf16x8 __attribute__((ext_vector_type(8)));
typedef short bf16x4 __attribute__((ext_vector_type(4)));
typedef float f32x4  __attribute__((ext_vector_type(4)));

static __device__ __forceinline__ short f2bf(float f) {
    union { float f; unsigned u; } v; v.f = f;
    unsigned r = v.u + 0x7fffu + ((v.u >> 16) & 1u);   // RNE
    return (short)(r >> 16);
}

// ---------------- workspace layout (float offsets) ----------------
enum : size_t {
    OFF_M     = 0,                               // [256][256]  (Wq^T Wk) * d^-0.5
    OFF_WIHT  = OFF_M    + 256 * 256,            // [256][768]
    OFF_WHHT  = OFF_WIHT + 256 * 768,            // [256][768]
    OFF_WVT   = OFF_WHHT + 256 * 768,            // [256][256]
    OFF_W1T   = OFF_WVT  + 256 * 256,            // [256][256]
    OFF_W2T   = OFF_W1T  + 256 * 256,            // [256][256]
    OFF_SLOTS = OFF_W2T  + 256 * 256,            // [64][8][256]
    OFF_SNEW  = OFF_SLOTS + BATCH * NSLOT * 256, // (unused, layout kept)
    OFF_QT    = OFF_SNEW  + BATCH * NSLOT * 256, // [64][8][256]
    OFF_H     = OFF_QT    + BATCH * NSLOT * 256, // (unused)
    OFF_UPD   = OFF_H     + BATCH * NSLOT * 256, // (unused)
    OFF_UPART = OFF_UPD   + BATCH * NSLOT * 256, // [64][NPART][8][256]
    OFF_LPART = OFF_UPART + (size_t)BATCH * NPART * NSLOT * 256, // [64][NPART][16] (l:0-7)
    OFF_XLN   = OFF_LPART + BATCH * NPART * 16,  // bf16 LN(x) token-major [64][4096][256]
    WS_FLOATS = OFF_XLN   + (size_t)BATCH * NTOK * 128
};

// ---------------- weight transposes (coalesced via LDS tile) ----------------
__global__ __launch_bounds__(256) void k_transpose(const float* __restrict__ w_ih,
                                                   const float* __restrict__ w_hh,
                                                   const float* __restrict__ wv,
                                                   const float* __restrict__ w1,
                                                   const float* __restrict__ w2,
                                                   float* __restrict__ ws) {
    int z = blockIdx.z;
    const float* src;
    float* dst;
    int R;
    if (z == 0)      { src = w_ih; dst = ws + OFF_WIHT; R = 768; }
    else if (z == 1) { src = w_hh; dst = ws + OFF_WHHT; R = 768; }
    else if (z == 2) { src = wv;   dst = ws + OFF_WVT;  R = 256; }
    else if (z == 3) { src = w1;   dst = ws + OFF_W1T;  R = 256; }
    else             { src = w2;   dst = ws + OFF_W2T;  R = 256; }
    if ((int)blockIdx.x * 32 >= R) return;
    __shared__ float tile[32][33];
    int lx = threadIdx.x & 31, ly = threadIdx.x >> 5;
    int r0 = blockIdx.x * 32, c0 = blockIdx.y * 32;
#pragma unroll
    for (int p = 0; p < 4; ++p)
        tile[ly + p * 8][lx] = src[(size_t)(r0 + ly + p * 8) * 256 + c0 + lx];
    __syncthreads();
#pragma unroll
    for (int p = 0; p < 4; ++p)
        dst[(size_t)(c0 + ly + p * 8) * R + r0 + lx] = tile[lx][ly + p * 8];
}

// ---------------- M = (Wq^T @ Wk) * d^-0.5 ----------------
__global__ __launch_bounds__(256) void k_m(const float* __restrict__ wq,
                                           const float* __restrict__ wk,
                                           float* __restrict__ ws) {
    int d = blockIdx.x, t = threadIdx.x;
    float acc = 0.f;
    for (int e = 0; e < 256; ++e)
        acc += wq[e * 256 + d] * wk[e * 256 + t];
    ws[OFF_M + d * 256 + t] = acc * 0.0625f; // 256^-0.5
}

// ---------------- slots init ----------------
__global__ __launch_bounds__(256) void k_init(const float* __restrict__ mu,
                                              const float* __restrict__ logsig,
                                              const float* __restrict__ noise,
                                              float* __restrict__ ws) {
    int i = blockIdx.x * 256 + threadIdx.x; // grid 512 -> 131072
    int d = i & 255;
    ws[OFF_SLOTS + i] = mu[d] + noise[i] * __expf(logsig[d]);
}

// ---------------- qt = LN(slots, g_sl) @ M  (prologue only) ----------------
__global__ __launch_bounds__(256) void k_qt(float* __restrict__ ws,
                                            const float* __restrict__ g_sl,
                                            const float* __restrict__ be_sl) {
    __shared__ float ln[2048];
    int chunk = blockIdx.x, b = blockIdx.y;
    int t = threadIdx.x, wave = t >> 6, lane = t & 63;
    const float* slots = ws + OFF_SLOTS + b * 2048;
    float4 gf = ((const float4*)g_sl)[lane];
    float4 bf = ((const float4*)be_sl)[lane];
#pragma unroll
    for (int rr = 0; rr < 2; ++rr) {
        int r = wave + rr * 4;
        float4 v = ((const float4*)(slots + r * 256))[lane];
        float s1 = v.x + v.y + v.z + v.w;
        float s2 = v.x * v.x + v.y * v.y + v.z * v.z + v.w * v.w;
#pragma unroll
        for (int m = 1; m < 64; m <<= 1) { s1 += __shfl_xor(s1, m); s2 += __shfl_xor(s2, m); }
        float mu = s1 * (1.f / 256.f);
        float rstd = rsqrtf(s2 * (1.f / 256.f) - mu * mu + EPS);
        float4 o;
        o.x = (v.x - mu) * rstd * gf.x + bf.x;
        o.y = (v.y - mu) * rstd * gf.y + bf.y;
        o.z = (v.z - mu) * rstd * gf.z + bf.z;
        o.w = (v.w - mu) * rstd * gf.w + bf.w;
        *((float4*)&ln[r * 256 + lane * 4]) = o;
    }
    __syncthreads();
    const float* M = ws + OFF_M;
    int k0 = t >> 6;               // wave-uniform
    int e = chunk * 64 + (t & 63);
    float a0 = 0.f, a1 = 0.f;
    for (int d = 0; d < 256; ++d) {
        float m = M[d * 256 + e];
        a0 += ln[k0 * 256 + d] * m;
        a1 += ln[(k0 + 4) * 256 + d] * m;
    }
    float* qt = ws + OFF_QT + b * 2048;
    qt[k0 * 256 + e] = a0;
    qt[(k0 + 4) * 256 + e] = a1;
}

// ---------------- MFMA flash attention, single bf16 copy ----------------
// P1: read fp32 x, LN in registers, write bf16 xln once, run the pass.
// !P1: read bf16 xln (loads ARE A-frags), prefetched across tiles.
// B-frags via proven in-LDS XOR-swizzled transpose (scatter af -> xT, gather).
template <bool P1>
__global__ __launch_bounds__(256) void k_attn_t(const float* __restrict__ x,
                                                const float* __restrict__ g_in,
                                                const float* __restrict__ be_in,
                                                float* __restrict__ ws) {
    int seg = blockIdx.x, b = blockIdx.y;
    int t = threadIdx.x;
    int w = t >> 6, lane = t & 63;
    int q = lane >> 4, s16 = lane & 15;

    __shared__ short qhi[8 * 264];       // bf16 qt (8 real slots only)
    __shared__ short xT[256 * 64];       // bf16 transpose tile, XOR-swizzled groups
    __shared__ short Etmp[16 * 72];      // E bf16, [slot][token]
    __shared__ float lsum[4][8];

    const float* qtg = ws + OFF_QT + b * 2048;
    for (int idx = t; idx < 8 * 264; idx += 256) {
        int s = idx >> 8;                // /264 approximated: idx < 2112, s = idx/264
        s = idx / 264;
        int d = idx - s * 264;
        qhi[idx] = (d < 256) ? f2bf(qtg[s * 256 + d]) : (short)0;
    }
    __syncthreads();

    bf16x8 qf[8];
#pragma unroll
    for (int i = 0; i < 8; ++i) {
        if (s16 < 8) qf[i] = *(const bf16x8*)&qhi[s16 * 264 + i * 32 + q * 8];
        else         qf[i] = (bf16x8){0, 0, 0, 0, 0, 0, 0, 0};
    }

    f32x4 U[4];
#pragma unroll
    for (int c = 0; c < 4; ++c) U[c] = (f32x4){0.f, 0.f, 0.f, 0.f};
    float lacc = 0.f;

    short* xln = (short*)(ws + OFF_XLN);
    int mytok = seg * 256 + w * 16 + s16;
    int g0 = ((w * 16 + s16) >> 3);
    int t7 = s16 & 7;

    bf16x8 af[8];
    if (!P1) {
        const short* xr = xln + ((size_t)b * NTOK + mytok) * 256 + q * 8;
#pragma unroll
        for (int i = 0; i < 8; ++i) af[i] = *(const bf16x8*)&xr[i * 32];
    }

    for (int tt = 0; tt < 4; ++tt) {
        int tok = mytok + tt * 64;
        if (P1) {
            // ---- fp32 load + LN + bf16 convert + write xln ----
            const float4* xp = (const float4*)(x + ((size_t)b * NTOK + tok) * 256 + q * 8);
            float4 xa[8], xb[8];
#pragma unroll
            for (int i = 0; i < 8; ++i) { xa[i] = xp[8 * i]; xb[i] = xp[8 * i + 1]; }
            float s1 = 0.f, s2 = 0.f;
#pragma unroll
            for (int i = 0; i < 8; ++i) {
                s1 += xa[i].x + xa[i].y + xa[i].z + xa[i].w + xb[i].x + xb[i].y + xb[i].z + xb[i].w;
                s2 += xa[i].x * xa[i].x + xa[i].y * xa[i].y + xa[i].z * xa[i].z + xa[i].w * xa[i].w
                    + xb[i].x * xb[i].x + xb[i].y * xb[i].y + xb[i].z * xb[i].z + xb[i].w * xb[i].w;
            }
            s1 += __shfl_xor(s1, 16); s2 += __shfl_xor(s2, 16);
            s1 += __shfl_xor(s1, 32); s2 += __shfl_xor(s2, 32);
            float mu = s1 * (1.f / 256.f);
            float rstd = rsqrtf(s2 * (1.f / 256.f) - mu * mu + EPS);
            short* xrow = xln + ((size_t)b * NTOK + tok) * 256;
#pragma unroll
            for (int i = 0; i < 8; ++i) {
                int dbase = i * 32 + q * 8;
                float4 gA = *(const float4*)&g_in[dbase];
                float4 gB = *(const float4*)&g_in[dbase + 4];
                float4 bA = *(const float4*)&be_in[dbase];
                float4 bB = *(const float4*)&be_in[dbase + 4];
                bf16x8 f;
                f[0] = f2bf((xa[i].x - mu) * rstd * gA.x + bA.x);
                f[1] = f2bf((xa[i].y - mu) * rstd * gA.y + bA.y);
                f[2] = f2bf((xa[i].z - mu) * rstd * gA.z + bA.z);
                f[3] = f2bf((xa[i].w - mu) * rstd * gA.w + bA.w);
                f[4] = f2bf((xb[i].x - mu) * rstd * gB.x + bB.x);
                f[5] = f2bf((xb[i].y - mu) * rstd * gB.y + bB.y);
                f[6] = f2bf((xb[i].z - mu) * rstd * gB.z + bB.z);
                f[7] = f2bf((xb[i].w - mu) * rstd * gB.w + bB.w);
                af[i] = f;
                *(bf16x8*)&xrow[i * 32 + q * 8] = f;
            }
        }

        // ---- QK^T: two independent MFMA chains ----
        f32x4 Lc0 = (f32x4){0.f, 0.f, 0.f, 0.f};
        f32x4 Lc1 = (f32x4){0.f, 0.f, 0.f, 0.f};
#pragma unroll
        for (int i = 0; i < 4; ++i) {
            Lc0 = __builtin_amdgcn_mfma_f32_16x16x32_bf16(af[i],     qf[i],     Lc0, 0, 0, 0);
            Lc1 = __builtin_amdgcn_mfma_f32_16x16x32_bf16(af[i + 4], qf[i + 4], Lc1, 0, 0, 0);
        }

        bf16x4 e2;
#pragma unroll
        for (int r = 0; r < 4; ++r) {
            float E = __expf(fminf(Lc0[r] + Lc1[r], 30.f));
            lacc += E;
            e2[r] = f2bf(E);
        }

        __syncthreads();   // (A) previous tile's xT/Etmp reads complete

        // ---- scatter transpose into LDS (XOR-swizzled, proven) ----
#pragma unroll
        for (int i = 0; i < 8; ++i) {
            int Ki = (4 * i + q) & 7;
            int dbase = i * 32 + q * 8;
            bf16x8 f = af[i];
#pragma unroll
            for (int e = 0; e < 8; ++e) {
                int gp = (g0 ^ e ^ Ki) & 7;
                xT[((dbase + e) << 6) + (gp << 3) + t7] = f[e];
            }
        }
        *(bf16x4*)&Etmp[s16 * 72 + w * 16 + q * 4] = e2;

        __syncthreads();   // (B) xT + Etmp ready

        // ---- prefetch next tile's A-frags (pure global, overlaps U-GEMM) ----
        bf16x8 afn[8];
        if (!P1 && tt < 3) {
            const short* xr = xln + ((size_t)b * NTOK + tok + 64) * 256 + q * 8;
#pragma unroll
            for (int i = 0; i < 8; ++i) afn[i] = *(const bf16x8*)&xr[i * 32];
        }

        // ---- U-GEMM: gather from xT (proven conflict-free) ----
        bf16x8 ea0 = *(const bf16x8*)&Etmp[s16 * 72 + q * 8];
        bf16x8 ea1 = *(const bf16x8*)&Etmp[s16 * 72 + 32 + q * 8];
#pragma unroll
        for (int c = 0; c < 4; ++c) {
            int d = (4 * w + c) * 16 + s16;
            int swz = (d ^ (d >> 3)) & 7;
            const short* row = &xT[d << 6];
            bf16x8 b0 = *(const bf16x8*)&row[((q ^ swz) & 7) << 3];
            bf16x8 b1 = *(const bf16x8*)&row[(((4 + q) ^ swz) & 7) << 3];
            U[c] = __builtin_amdgcn_mfma_f32_16x16x32_bf16(ea0, b0, U[c], 0, 0, 0);
            U[c] = __builtin_amdgcn_mfma_f32_16x16x32_bf16(ea1, b1, U[c], 0, 0, 0);
        }

        if (!P1 && tt < 3) {
#pragma unroll
            for (int i = 0; i < 8; ++i) af[i] = afn[i];
        }
    }

    // ---- reduce l across quads/waves; store partials ----
    lacc += __shfl_xor(lacc, 16); lacc += __shfl_xor(lacc, 32);
    __syncthreads();
    if (q == 0 && s16 < 8) lsum[w][s16] = lacc;
    __syncthreads();
    float* lpart = ws + OFF_LPART + (size_t)(b * NPART + seg) * 16;
    if (t < 8) lpart[t] = lsum[0][t] + lsum[1][t] + lsum[2][t] + lsum[3][t];
    float* up = ws + OFF_UPART + (size_t)(b * NPART + seg) * NSLOT * 256;
#pragma unroll
    for (int c = 0; c < 4; ++c) {
        int d = (4 * w + c) * 16 + s16;
#pragma unroll
        for (int r = 0; r < 4; ++r) {
            int slot = q * 4 + r;
            if (slot < 8) up[slot * 256 + d] = U[c][r];
        }
    }
}

// ---------------- wave-per-row LN over 2 rows of [2][256] LDS ----------------
static __device__ __forceinline__ void ln_row2(const float* src, float* dst,
                                               const float* __restrict__ g,
                                               const float* __restrict__ be,
                                               int wave, int lane) {
    if (wave < 2) {
        float4 v = *(const float4*)(src + wave * 256 + lane * 4);
        float s1 = v.x + v.y + v.z + v.w;
        float s2 = v.x * v.x + v.y * v.y + v.z * v.z + v.w * v.w;
#pragma unroll
        for (int m = 1; m < 64; m <<= 1) { s1 += __shfl_xor(s1, m); s2 += __shfl_xor(s2, m); }
        float mu = s1 * (1.f / 256.f);
        float rstd = rsqrtf(s2 * (1.f / 256.f) - mu * mu + EPS);
        float4 gf = ((const float4*)g)[lane];
        float4 bf = ((const float4*)be)[lane];
        float4 o;
        o.x = (v.x - mu) * rstd * gf.x + bf.x;
        o.y = (v.y - mu) * rstd * gf.y + bf.y;
        o.z = (v.z - mu) * rstd * gf.z + bf.z;
        o.w = (v.w - mu) * rstd * gf.w + bf.w;
        *(float4*)(dst + wave * 256 + lane * 4) = o;
    }
}

// ---------------- fused slot pipeline: combine -> updates -> GRU -> MLP -> (qt | out) ----------------
__global__ __launch_bounds__(512) void k_fused(float* __restrict__ ws,
                                               const float* __restrict__ b_ih,
                                               const float* __restrict__ b_hh,
                                               const float* __restrict__ g_ff,
                                               const float* __restrict__ be_ff,
                                               const float* __restrict__ b1p,
                                               const float* __restrict__ b2p,
                                               const float* __restrict__ g_sl,
                                               const float* __restrict__ be_sl,
                                               float* __restrict__ dout) {
    __shared__ __align__(16) float uc[2][256], upd[2][256], sl[2][256], snew[2][256];
    __shared__ __align__(16) float lnb[2][256], hbuf[2][256], so[2][256];
    __shared__ float lsv[2];

    int sp = blockIdx.x, b = blockIdx.y, t = threadIdx.x;
    int s0 = sp * 2;
    int s = t >> 8, d = t & 255;          // s wave-uniform
    int wave = t >> 6, lane = t & 63;

    // ---- Stage A: combine l partials for the 2 slots ----
    if (t < 32) {
        int ss = t >> 4, g = t & 15;
        float lv = ws[OFF_LPART + (size_t)(b * NPART + g) * 16 + s0 + ss];
#pragma unroll
        for (int m = 1; m < 16; m <<= 1) lv += __shfl_xor(lv, m);
        if ((t & 15) == 0) lsv[ss] = lv;
    }

    // ---- Stage B: combine U partials; load old slots ----
    const float* up0 = ws + OFF_UPART + (size_t)b * NPART * NSLOT * 256 + (s0 + s) * 256 + d;
    float acc = 0.f;
#pragma unroll
    for (int g = 0; g < NPART; ++g) acc += up0[(size_t)g * NSLOT * 256];
    sl[s][d] = ws[OFF_SLOTS + (size_t)b * 2048 + (s0 + s) * 256 + d];
    __syncthreads();
    uc[s][d] = acc / lsv[s];
    __syncthreads();

    // ---- Stage C: upd = uc @ WvT ----
    {
        const float* WvT = ws + OFF_WVT;
        float o = 0.f;
        for (int dd = 0; dd < 256; ++dd) o += uc[s][dd] * WvT[dd * 256 + d];
        upd[s][d] = o;
    }
    __syncthreads();

    // ---- Stage D: GRU cell ----
    {
        const float* WihT = ws + OFF_WIHT;
        const float* WhhT = ws + OFF_WHHT;
        float ar = 0.f, az = 0.f, an = 0.f, hr = 0.f, hz = 0.f, hn = 0.f;
        for (int dd = 0; dd < 256; ++dd) {
            float ud = upd[s][dd], sd = sl[s][dd];
            const float* wi = WihT + dd * 768;
            const float* wh = WhhT + dd * 768;
            ar += ud * wi[d];       az += ud * wi[256 + d]; an += ud * wi[512 + d];
            hr += sd * wh[d];       hz += sd * wh[256 + d]; hn += sd * wh[512 + d];
        }
        float rg = 1.f / (1.f + __expf(-(ar + b_ih[d] + hr + b_hh[d])));
        float zg = 1.f / (1.f + __expf(-(az + b_ih[256 + d] + hz + b_hh[256 + d])));
        float ng = tanhf(an + b_ih[512 + d] + rg * (hn + b_hh[512 + d]));
        snew[s][d] = (1.f - zg) * ng + zg * sl[s][d];
    }
    __syncthreads();

    // ---- Stage E: LN(snew, g_ff, be_ff) ----
    ln_row2(&snew[0][0], &lnb[0][0], g_ff, be_ff, wave, lane);
    __syncthreads();

    // ---- Stage F: h = relu(lnb @ W1T + b1) ----
    {
        const float* W1T = ws + OFF_W1T;
        float o = 0.f;
        for (int dd = 0; dd < 256; ++dd) o += lnb[s][dd] * W1T[dd * 256 + d];
        hbuf[s][d] = fmaxf(o + b1p[d], 0.f);
    }
    __syncthreads();

    // ---- Stage G: slots_out = snew + h @ W2T + b2 ----
    {
        const float* W2T = ws + OFF_W2T;
        float o = 0.f;
        for (int dd = 0; dd < 256; ++dd) o += hbuf[s][dd] * W2T[dd * 256 + d];
        float r = snew[s][d] + o + b2p[d];
        so[s][d] = r;
        ws[OFF_SLOTS + (size_t)b * 2048 + (s0 + s) * 256 + d] = r;
        if (dout) dout[(size_t)b * 2048 + (s0 + s) * 256 + d] = r;
    }

    // ---- Stage H (non-final iters): qt = LN(slots_out, g_sl) @ M ----
    if (!dout) {
        __syncthreads();
        ln_row2(&so[0][0], &lnb[0][0], g_sl, be_sl, wave, lane);
        __syncthreads();
        const float* M = ws + OFF_M;
        float o = 0.f;
        for (int dd = 0; dd < 256; ++dd) o += lnb[s][dd] * M[dd * 256 + d];
        ws[OFF_QT + (size_t)b * 2048 + (s0 + s) * 256 + d] = o;
    }
}

extern "C" void kernel_launch(void* const* d_in, const int* in_sizes, int n_in,
                              void* d_out, int out_size, void* d_ws, size_t ws_size,
                              hipStream_t stream) {
    const float* x      = (const float*)d_in[0];
    const float* noise  = (const float*)d_in[1];
    const float* mu     = (const float*)d_in[2];
    const float* logsig = (const float*)d_in[3];
    const float* Wq     = (const float*)d_in[4];
    const float* Wk     = (const float*)d_in[5];
    const float* Wv     = (const float*)d_in[6];
    const float* W_ih   = (const float*)d_in[7];
    const float* W_hh   = (const float*)d_in[8];
    const float* b_ih   = (const float*)d_in[9];
    const float* b_hh   = (const float*)d_in[10];
    const float* W1     = (const float*)d_in[11];
    const float* b1     = (const float*)d_in[12];
    const float* W2     = (const float*)d_in[13];
    const float* b2     = (const float*)d_in[14];
    const float* g_in   = (const float*)d_in[15];
    const float* be_in  = (const float*)d_in[16];
    const float* g_sl   = (const float*)d_in[17];
    const float* be_sl  = (const float*)d_in[18];
    const float* g_ff   = (const float*)d_in[19];
    const float* be_ff  = (const float*)d_in[20];
    float* ws = (float*)d_ws;
    float* out = (float*)d_out;

    hipLaunchKernelGGL(k_transpose, dim3(24, 8, 5), dim3(256), 0, stream, W_ih, W_hh, Wv, W1, W2, ws);
    hipLaunchKernelGGL(k_m, dim3(256), dim3(256), 0, stream, Wq, Wk, ws);
    hipLaunchKernelGGL(k_init, dim3(512), dim3(256), 0, stream, mu, logsig, noise, ws);
    hipLaunchKernelGGL(k_qt, dim3(4, 64), dim3(256), 0, stream, ws, g_sl, be_sl);
    for (int it = 0; it < ITERS; ++it) {
        if (it == 0)
            hipLaunchKernelGGL((k_attn_t<true>),  dim3(SEGB, 64), dim3(256), 0, stream, x, g_in, be_in, ws);
        else
            hipLaunchKernelGGL((k_attn_t<false>), dim3(SEGB, 64), dim3(256), 0, stream, x, g_in, be_in, ws);
        hipLaunchKernelGGL(k_fused, dim3(4, 64), dim3(512), 0, stream, ws,
                           b_ih, b_hh, g_ff, be_ff, b1, b2, g_sl, be_sl,
                           (it == ITERS - 1) ? out : nullptr);
    }
}